// Round 1
// baseline (214.966 us; speedup 1.0000x reference)
//
#include <hip/hip_runtime.h>
#include <math.h>

#define NNODE 32768   // B*N
#define EE 128
constexpr float SCALE = 0.08838834764831845f; // 1/sqrt(128)

// ---------------- kernel 1: fold weights -------------------------------
// Mcat[e][col], col = dir*384 + which*128 + f  (which: 0=q,1=k,2=v)
// Mcat[e][col] = sum_c W_dir_which[e][c] * ipw_dir[which*128 + f][c]
// bcat[col]    = ipb_dir[which*128 + f]
// Pcat[e2][f], e2 = dir*128 + e :  sum_c lin_w[f][dir*128+c] * ow_dir[c][e]
// bh[f] = lin_b[f] + sum_c ob_in[c]*lin_w[f][c] + ob_out[c]*lin_w[f][128+c]
__global__ __launch_bounds__(256) void fuse_weights(
    const float* __restrict__ Wq_in, const float* __restrict__ Wk_in,
    const float* __restrict__ Wv_in, const float* __restrict__ ipw_in,
    const float* __restrict__ ipb_in, const float* __restrict__ ow_in,
    const float* __restrict__ ob_in,
    const float* __restrict__ Wq_out, const float* __restrict__ Wk_out,
    const float* __restrict__ Wv_out, const float* __restrict__ ipw_out,
    const float* __restrict__ ipb_out, const float* __restrict__ ow_out,
    const float* __restrict__ ob_out,
    const float* __restrict__ lin_w, const float* __restrict__ lin_b,
    float* __restrict__ Mcat, float* __restrict__ bcat,
    float* __restrict__ Pcat, float* __restrict__ bh)
{
    int t = blockIdx.x * 256 + threadIdx.x;
    if (t < 98304) {
        int col = t % 768, e = t / 768;
        int dir = col / 384, rem = col % 384;
        int which = rem / 128, f = rem % 128;
        const float* W = (dir == 0)
            ? (which == 0 ? Wq_in : which == 1 ? Wk_in : Wv_in)
            : (which == 0 ? Wq_out : which == 1 ? Wk_out : Wv_out);
        const float* ipw = (dir == 0) ? ipw_in : ipw_out;
        const float* wrow = ipw + (which * EE + f) * EE;
        const float* Wrow = W + e * EE;
        float s = 0.f;
        for (int c = 0; c < EE; ++c) s += Wrow[c] * wrow[c];
        Mcat[e * 768 + col] = s;
    } else if (t < 98304 + 768) {
        int col = t - 98304;
        int dir = col / 384, rem = col % 384;
        int which = rem / 128, f = rem % 128;
        const float* ipb = (dir == 0) ? ipb_in : ipb_out;
        bcat[col] = ipb[which * EE + f];
    } else if (t < 98304 + 768 + 32768) {
        int u = t - (98304 + 768);
        int e2 = u / 128, f = u % 128;
        int dir = e2 / 128, e = e2 % 128;
        const float* ow = (dir == 0) ? ow_in : ow_out;
        float s = 0.f;
        for (int c = 0; c < EE; ++c)
            s += lin_w[f * 256 + dir * 128 + c] * ow[c * EE + e];
        Pcat[e2 * 128 + f] = s;
    } else if (t < 98304 + 768 + 32768 + 128) {
        int f = t - (98304 + 768 + 32768);
        float s = lin_b[f];
        for (int c = 0; c < EE; ++c)
            s += ob_in[c] * lin_w[f * 256 + c] + ob_out[c] * lin_w[f * 256 + 128 + c];
        bh[f] = s;
    }
}

// ---------------- kernel 2/4: 64x64-tile f32 GEMM + bias (+ELU) --------
// C[M x ldc](cols bn..bn+63) = A[M x lda](K cols) * Bw[K x ldb] + bias
template<int K, bool ELU>
__global__ __launch_bounds__(256) void gemm64(
    const float* __restrict__ A, int lda,
    const float* __restrict__ Bw, int ldb,
    const float* __restrict__ bias,
    float* __restrict__ C, int ldc)
{
    __shared__ float As[64][68];
    __shared__ float Bs[64][68];
    const int tid = threadIdx.x;
    const int bm = blockIdx.x * 64;
    const int bn = blockIdx.y * 64;
    const int tx = tid & 15, ty = tid >> 4;
    float acc[4][4] = {};

    for (int k0 = 0; k0 < K; k0 += 64) {
        #pragma unroll
        for (int i = 0; i < 4; ++i) {
            int v = i * 256 + tid;      // 0..1023
            int m = v >> 4;             // 0..63
            int c4 = v & 15;            // 0..15
            float4 a = *(const float4*)&A[(size_t)(bm + m) * lda + k0 + c4 * 4];
            *(float4*)&As[m][c4 * 4] = a;
            float4 b = *(const float4*)&Bw[(size_t)(k0 + m) * ldb + bn + c4 * 4];
            *(float4*)&Bs[m][c4 * 4] = b;
        }
        __syncthreads();
        #pragma unroll
        for (int kc = 0; kc < 16; ++kc) {
            float a_[4][4], b_[4][4];
            #pragma unroll
            for (int i = 0; i < 4; ++i) {
                float4 ta = *(const float4*)&As[ty * 4 + i][kc * 4];
                a_[i][0] = ta.x; a_[i][1] = ta.y; a_[i][2] = ta.z; a_[i][3] = ta.w;
                float4 tb = *(const float4*)&Bs[kc * 4 + i][tx * 4];
                b_[i][0] = tb.x; b_[i][1] = tb.y; b_[i][2] = tb.z; b_[i][3] = tb.w;
            }
            #pragma unroll
            for (int c = 0; c < 4; ++c)
                #pragma unroll
                for (int i = 0; i < 4; ++i)
                    #pragma unroll
                    for (int j = 0; j < 4; ++j)
                        acc[i][j] += a_[i][c] * b_[c][j];
        }
        __syncthreads();
    }

    #pragma unroll
    for (int i = 0; i < 4; ++i) {
        int row = bm + ty * 4 + i;
        float4 o;
        float* po = &o.x;
        #pragma unroll
        for (int j = 0; j < 4; ++j) {
            int colg = bn + tx * 4 + j;
            float v2 = acc[i][j] + bias[colg];
            if (ELU) v2 = v2 > 0.f ? v2 : (__expf(v2) - 1.f);
            po[j] = v2;
        }
        *(float4*)&C[(size_t)row * ldc + bn + tx * 4] = o;
    }
}

// ---------------- kernel 3: per-node 9-slot attention ------------------
// One wave per (node, dir). QKV row layout: [q_in k_in v_in q_out k_out v_out]
__global__ __launch_bounds__(256) void attn_kernel(
    const float* __restrict__ QKV,
    const int* __restrict__ in_idx, const int* __restrict__ out_idx,
    const int* __restrict__ in_mask, const int* __restrict__ out_mask,
    float* __restrict__ CTX)
{
    int wid = blockIdx.x * 4 + (threadIdx.x >> 6);
    int lane = threadIdx.x & 63;
    int dir = wid & 1;
    int node = wid >> 1;           // 0..32767
    int b = node >> 13;            // node / 8192
    const int* idx = dir == 0 ? in_idx : out_idx;
    const int* msk = dir == 0 ? in_mask : out_mask;
    const int qoff = dir * 384;

    const float* qrow = QKV + (size_t)node * 768 + qoff;
    float2 q = *(const float2*)&qrow[lane * 2];

    float sc[9];
    float2 vv[9];
    bool valid[9];
    // slot 0: self
    {
        const float* krow = qrow + 128;
        float2 k = *(const float2*)&krow[lane * 2];
        vv[0] = *(const float2*)&krow[128 + lane * 2];
        sc[0] = q.x * k.x + q.y * k.y;
        valid[0] = true;
    }
    #pragma unroll
    for (int s = 1; s < 9; ++s) {
        int ii = idx[(size_t)node * 8 + (s - 1)];
        int mm = msk[(size_t)node * 8 + (s - 1)];
        valid[s] = (mm != 0);
        int g = (b << 13) + ii;
        const float* krow = QKV + (size_t)g * 768 + qoff + 128;
        float2 k = *(const float2*)&krow[lane * 2];
        vv[s] = *(const float2*)&krow[128 + lane * 2];
        sc[s] = q.x * k.x + q.y * k.y;
    }
    // butterfly-reduce each of the 9 dots across the 64-lane wave
    #pragma unroll
    for (int s = 0; s < 9; ++s) {
        float x = sc[s];
        #pragma unroll
        for (int o = 32; o > 0; o >>= 1) x += __shfl_xor(x, o);
        sc[s] = x * SCALE;
    }
    // masked softmax over 9 slots (slot 0 always valid)
    float m = sc[0];
    #pragma unroll
    for (int s = 1; s < 9; ++s) if (valid[s] && sc[s] > m) m = sc[s];
    float w[9], wsum = 0.f;
    #pragma unroll
    for (int s = 0; s < 9; ++s) {
        w[s] = valid[s] ? __expf(sc[s] - m) : 0.f;
        wsum += w[s];
    }
    float inv = 1.f / wsum;
    float2 c = {0.f, 0.f};
    #pragma unroll
    for (int s = 0; s < 9; ++s) { c.x += w[s] * vv[s].x; c.y += w[s] * vv[s].y; }
    c.x *= inv; c.y *= inv;
    *(float2*)&CTX[(size_t)node * 256 + dir * 128 + lane * 2] = c;
}

// ---------------- launch ----------------------------------------------
extern "C" void kernel_launch(void* const* d_in, const int* in_sizes, int n_in,
                              void* d_out, int out_size, void* d_ws, size_t ws_size,
                              hipStream_t stream) {
    const float* X        = (const float*)d_in[0];
    const int*   in_idx   = (const int*)d_in[1];
    const int*   out_idx  = (const int*)d_in[2];
    const int*   in_mask  = (const int*)d_in[3];
    const int*   out_mask = (const int*)d_in[4];
    const float* Wq_in  = (const float*)d_in[5];
    const float* Wk_in  = (const float*)d_in[6];
    const float* Wv_in  = (const float*)d_in[7];
    const float* ipw_in = (const float*)d_in[8];
    const float* ipb_in = (const float*)d_in[9];
    const float* ow_in  = (const float*)d_in[10];
    const float* ob_in  = (const float*)d_in[11];
    const float* Wq_out  = (const float*)d_in[12];
    const float* Wk_out  = (const float*)d_in[13];
    const float* Wv_out  = (const float*)d_in[14];
    const float* ipw_out = (const float*)d_in[15];
    const float* ipb_out = (const float*)d_in[16];
    const float* ow_out  = (const float*)d_in[17];
    const float* ob_out  = (const float*)d_in[18];
    const float* lin_w   = (const float*)d_in[19];
    const float* lin_b   = (const float*)d_in[20];

    float* ws   = (float*)d_ws;
    float* QKV  = ws;                                  // 32768*768
    float* CTX  = QKV + (size_t)NNODE * 768;           // 32768*256
    float* Mcat = CTX + (size_t)NNODE * 256;           // 128*768
    float* bcat = Mcat + 128 * 768;                    // 768
    float* Pcat = bcat + 768;                          // 256*128
    float* bh   = Pcat + 256 * 128;                    // 128

    fuse_weights<<<516, 256, 0, stream>>>(
        Wq_in, Wk_in, Wv_in, ipw_in, ipb_in, ow_in, ob_in,
        Wq_out, Wk_out, Wv_out, ipw_out, ipb_out, ow_out, ob_out,
        lin_w, lin_b, Mcat, bcat, Pcat, bh);

    gemm64<128, false><<<dim3(512, 12), 256, 0, stream>>>(
        X, 128, Mcat, 768, bcat, QKV, 768);

    attn_kernel<<<NNODE * 2 / 4, 256, 0, stream>>>(
        QKV, in_idx, out_idx, in_mask, out_mask, CTX);

    gemm64<256, true><<<dim3(512, 2), 256, 0, stream>>>(
        CTX, 256, Pcat, 128, bh, (float*)d_out, 128);
}

// Round 2
// 91.819 us; speedup vs baseline: 2.3412x; 2.3412x over previous
//
#include <hip/hip_runtime.h>
#include <math.h>

#define NNODE 32768   // B*N
#define EE 128
constexpr float SCALE = 0.08838834764831845f; // 1/sqrt(128)

typedef unsigned short u16;
typedef __bf16 bf16x8 __attribute__((ext_vector_type(8)));
typedef float f32x4 __attribute__((ext_vector_type(4)));

__device__ __forceinline__ u16 f2bf(float f) {
    unsigned u = __float_as_uint(f);
    u += 0x7fff + ((u >> 16) & 1);       // RNE
    return (u16)(u >> 16);
}
__device__ __forceinline__ float bf2f(u16 h) {
    return __uint_as_float(((unsigned)h) << 16);
}

// async global->LDS, 16B per lane; LDS dest must be wave-uniform base
__device__ __forceinline__ void gl_lds16(const void* g, void* l) {
    __builtin_amdgcn_global_load_lds(
        (const __attribute__((address_space(1))) unsigned int*)(uintptr_t)g,
        (__attribute__((address_space(3))) unsigned int*)(unsigned int)(uintptr_t)l,
        16, 0, 0);
}

// ---------------- kernel 0: X f32 -> bf16 ------------------------------
__global__ __launch_bounds__(256) void xconv(const float* __restrict__ X,
                                             u16* __restrict__ Xb)
{
    int t = blockIdx.x * 256 + threadIdx.x;   // one thread = 8 elems
    float4 a = *(const float4*)&X[(size_t)t * 8];
    float4 b = *(const float4*)&X[(size_t)t * 8 + 4];
    u16 o[8] = { f2bf(a.x), f2bf(a.y), f2bf(a.z), f2bf(a.w),
                 f2bf(b.x), f2bf(b.y), f2bf(b.z), f2bf(b.w) };
    *(uint4*)&Xb[(size_t)t * 8] = *(const uint4*)o;
}

// ---------------- kernel 1: fold weights -------------------------------
// McatbT[col][e]  (bf16, [768][128])  col = dir*384 + which*128 + f
// bcat[col] f32
// PcatbT[f][e2]   (bf16, [128][256])  e2 = dir*128 + e
// bh[f] f32
__global__ __launch_bounds__(256) void fuse_weights(
    const float* __restrict__ Wq_in, const float* __restrict__ Wk_in,
    const float* __restrict__ Wv_in, const float* __restrict__ ipw_in,
    const float* __restrict__ ipb_in, const float* __restrict__ ow_in,
    const float* __restrict__ ob_in,
    const float* __restrict__ Wq_out, const float* __restrict__ Wk_out,
    const float* __restrict__ Wv_out, const float* __restrict__ ipw_out,
    const float* __restrict__ ipb_out, const float* __restrict__ ow_out,
    const float* __restrict__ ob_out,
    const float* __restrict__ lin_w, const float* __restrict__ lin_b,
    u16* __restrict__ McatbT, float* __restrict__ bcat,
    u16* __restrict__ PcatbT, float* __restrict__ bh)
{
    int t = blockIdx.x * 256 + threadIdx.x;
    if (t < 98304) {
        int col = t % 768, e = t / 768;
        int dir = col / 384, rem = col % 384;
        int which = rem / 128, f = rem % 128;
        const float* W = (dir == 0)
            ? (which == 0 ? Wq_in : which == 1 ? Wk_in : Wv_in)
            : (which == 0 ? Wq_out : which == 1 ? Wk_out : Wv_out);
        const float* ipw = (dir == 0) ? ipw_in : ipw_out;
        const float* wrow = ipw + (which * EE + f) * EE;
        const float* Wrow = W + e * EE;
        float s = 0.f;
        for (int c = 0; c < EE; ++c) s += Wrow[c] * wrow[c];
        McatbT[(size_t)col * 128 + e] = f2bf(s);
    } else if (t < 98304 + 768) {
        int col = t - 98304;
        int dir = col / 384, rem = col % 384;
        int which = rem / 128, f = rem % 128;
        const float* ipb = (dir == 0) ? ipb_in : ipb_out;
        bcat[col] = ipb[which * EE + f];
    } else if (t < 98304 + 768 + 32768) {
        int u = t - (98304 + 768);
        int e2 = u / 128, f = u % 128;
        int dir = e2 / 128, e = e2 % 128;
        const float* ow = (dir == 0) ? ow_in : ow_out;
        float s = 0.f;
        for (int c = 0; c < EE; ++c)
            s += lin_w[f * 256 + dir * 128 + c] * ow[c * EE + e];
        PcatbT[(size_t)f * 256 + e2] = f2bf(s);
    } else if (t < 98304 + 768 + 32768 + 128) {
        int f = t - (98304 + 768 + 32768);
        float s = lin_b[f];
        for (int c = 0; c < EE; ++c)
            s += ob_in[c] * lin_w[f * 256 + c] + ob_out[c] * lin_w[f * 256 + 128 + c];
        bh[f] = s;
    }
}

// ---------------- kernel 2/4: MFMA bf16 GEMM ---------------------------
// C[M][ldc] = A[M][KTOT] * BT[N][KTOT]^T + bias  (tile 128x128, 4 waves)
// LDS XOR-swizzle: 16B chunk cb within a row stored at cb ^ (r&7);
// achieved by pre-swizzling the GLOBAL source (linear LDS dest, rule #21).
template<int KTOT, bool ELU_F32>
__global__ __launch_bounds__(256) void gemm_mfma(
    const u16* __restrict__ A,
    const u16* __restrict__ BT,
    const float* __restrict__ bias,
    void* __restrict__ Cout, int ldc)
{
    __shared__ __align__(16) u16 As[128 * 128];
    __shared__ __align__(16) u16 Bs[128 * 128];
    const int tid  = threadIdx.x;
    const int lane = tid & 63;
    const int wid  = tid >> 6;
    const int bm = blockIdx.x * 128;
    const int bn = blockIdx.y * 128;
    const int wr = wid >> 1, wc = wid & 1;
    const int l15 = lane & 15, l4 = lane >> 4;

    f32x4 acc[4][4] = {};

    for (int k0 = 0; k0 < KTOT; k0 += 128) {
        // ---- stage 128x128 bf16 A-tile and B-tile (16B/lane async) ----
        #pragma unroll
        for (int i = 0; i < 8; ++i) {
            int c = i * 256 + tid;          // chunk id 0..2047
            int r = c >> 4, cb = c & 15;
            int col = k0 + 8 * (cb ^ (r & 7));   // pre-swizzled source
            gl_lds16(&A[(size_t)(bm + r) * KTOT + col], &As[(size_t)(c - lane) * 8]);
            gl_lds16(&BT[(size_t)(bn + r) * KTOT + col], &Bs[(size_t)(c - lane) * 8]);
        }
        __syncthreads();

        // ---- 64 MFMA per wave ----
        #pragma unroll
        for (int ks = 0; ks < 4; ++ks) {
            bf16x8 a[4], b[4];
            #pragma unroll
            for (int mr = 0; mr < 4; ++mr) {
                int r = wr * 64 + mr * 16 + l15;
                int kb = ks * 4 + l4;
                a[mr] = *(const bf16x8*)((const char*)As + r * 256 + ((kb ^ (r & 7)) << 4));
            }
            #pragma unroll
            for (int nc = 0; nc < 4; ++nc) {
                int r = wc * 64 + nc * 16 + l15;
                int kb = ks * 4 + l4;
                b[nc] = *(const bf16x8*)((const char*)Bs + r * 256 + ((kb ^ (r & 7)) << 4));
            }
            #pragma unroll
            for (int mr = 0; mr < 4; ++mr)
                #pragma unroll
                for (int nc = 0; nc < 4; ++nc)
                    acc[mr][nc] = __builtin_amdgcn_mfma_f32_16x16x32_bf16(
                        a[mr], b[nc], acc[mr][nc], 0, 0, 0);
        }
        __syncthreads();
    }

    // ---- epilogue: D row=(l>>4)*4+j, col=l&15 (m89/m91-verified) ----
    #pragma unroll
    for (int nc = 0; nc < 4; ++nc) {
        int col = bn + wc * 64 + nc * 16 + l15;
        float bv = bias[col];
        #pragma unroll
        for (int mr = 0; mr < 4; ++mr) {
            #pragma unroll
            for (int j = 0; j < 4; ++j) {
                int row = bm + wr * 64 + mr * 16 + l4 * 4 + j;
                float v = acc[mr][nc][j] + bv;
                if (ELU_F32) {
                    v = v > 0.f ? v : (__expf(v) - 1.f);
                    ((float*)Cout)[(size_t)row * ldc + col] = v;
                } else {
                    ((u16*)Cout)[(size_t)row * ldc + col] = f2bf(v);
                }
            }
        }
    }
}

// ---------------- kernel 3: per-node 9-slot attention (bf16 QKV) -------
__global__ __launch_bounds__(256) void attn_kernel(
    const u16* __restrict__ QKV,
    const int* __restrict__ in_idx, const int* __restrict__ out_idx,
    const int* __restrict__ in_mask, const int* __restrict__ out_mask,
    u16* __restrict__ CTX)
{
    int wid = blockIdx.x * 4 + (threadIdx.x >> 6);
    int lane = threadIdx.x & 63;
    int dir = wid & 1;
    int node = wid >> 1;           // 0..32767
    int b = node >> 13;
    const int* idx = dir == 0 ? in_idx : out_idx;
    const int* msk = dir == 0 ? in_mask : out_mask;
    const int qoff = dir * 384;

    const u16* qrow = QKV + (size_t)node * 768 + qoff;
    ushort2 qu = *(const ushort2*)&qrow[lane * 2];
    float qx = bf2f(qu.x), qy = bf2f(qu.y);

    float sc[9], vx[9], vy[9];
    bool valid[9];
    {
        const u16* krow = qrow + 128;
        ushort2 ku = *(const ushort2*)&krow[lane * 2];
        ushort2 vu = *(const ushort2*)&krow[128 + lane * 2];
        sc[0] = qx * bf2f(ku.x) + qy * bf2f(ku.y);
        vx[0] = bf2f(vu.x); vy[0] = bf2f(vu.y);
        valid[0] = true;
    }
    #pragma unroll
    for (int s = 1; s < 9; ++s) {
        int ii = idx[(size_t)node * 8 + (s - 1)];
        int mm = msk[(size_t)node * 8 + (s - 1)];
        valid[s] = (mm != 0);
        const u16* krow = QKV + (size_t)((b << 13) + ii) * 768 + qoff + 128;
        ushort2 ku = *(const ushort2*)&krow[lane * 2];
        ushort2 vu = *(const ushort2*)&krow[128 + lane * 2];
        sc[s] = qx * bf2f(ku.x) + qy * bf2f(ku.y);
        vx[s] = bf2f(vu.x); vy[s] = bf2f(vu.y);
    }
    #pragma unroll
    for (int s = 0; s < 9; ++s) {
        float x = sc[s];
        #pragma unroll
        for (int o = 32; o > 0; o >>= 1) x += __shfl_xor(x, o);
        sc[s] = x * SCALE;
    }
    float m = sc[0];
    #pragma unroll
    for (int s = 1; s < 9; ++s) if (valid[s] && sc[s] > m) m = sc[s];
    float w[9], wsum = 0.f;
    #pragma unroll
    for (int s = 0; s < 9; ++s) {
        w[s] = valid[s] ? __expf(sc[s] - m) : 0.f;
        wsum += w[s];
    }
    float inv = 1.f / wsum;
    float cx = 0.f, cy = 0.f;
    #pragma unroll
    for (int s = 0; s < 9; ++s) { cx += w[s] * vx[s]; cy += w[s] * vy[s]; }
    ushort2 o; o.x = f2bf(cx * inv); o.y = f2bf(cy * inv);
    *(ushort2*)&CTX[(size_t)node * 256 + dir * 128 + lane * 2] = o;
}

// ---------------- launch ----------------------------------------------
extern "C" void kernel_launch(void* const* d_in, const int* in_sizes, int n_in,
                              void* d_out, int out_size, void* d_ws, size_t ws_size,
                              hipStream_t stream) {
    const float* X        = (const float*)d_in[0];
    const int*   in_idx   = (const int*)d_in[1];
    const int*   out_idx  = (const int*)d_in[2];
    const int*   in_mask  = (const int*)d_in[3];
    const int*   out_mask = (const int*)d_in[4];
    const float* Wq_in  = (const float*)d_in[5];
    const float* Wk_in  = (const float*)d_in[6];
    const float* Wv_in  = (const float*)d_in[7];
    const float* ipw_in = (const float*)d_in[8];
    const float* ipb_in = (const float*)d_in[9];
    const float* ow_in  = (const float*)d_in[10];
    const float* ob_in  = (const float*)d_in[11];
    const float* Wq_out  = (const float*)d_in[12];
    const float* Wk_out  = (const float*)d_in[13];
    const float* Wv_out  = (const float*)d_in[14];
    const float* ipw_out = (const float*)d_in[15];
    const float* ipb_out = (const float*)d_in[16];
    const float* ow_out  = (const float*)d_in[17];
    const float* ob_out  = (const float*)d_in[18];
    const float* lin_w   = (const float*)d_in[19];
    const float* lin_b   = (const float*)d_in[20];

    u16* wsu    = (u16*)d_ws;
    u16* Xb     = wsu;                       // 32768*128      = 4,194,304
    u16* QKVb   = Xb + (size_t)4194304;      // 32768*768      = 25,165,824
    u16* CTXb   = QKVb + (size_t)25165824;   // 32768*256      = 8,388,608
    u16* McatbT = CTXb + (size_t)8388608;    // 768*128        = 98,304
    u16* PcatbT = McatbT + 98304;            // 128*256        = 32,768
    float* bcat = (float*)(PcatbT + 32768);  // 768 f32 (16B-aligned)
    float* bh   = bcat + 768;                // 128 f32

    xconv<<<2048, 256, 0, stream>>>(X, Xb);

    fuse_weights<<<516, 256, 0, stream>>>(
        Wq_in, Wk_in, Wv_in, ipw_in, ipb_in, ow_in, ob_in,
        Wq_out, Wk_out, Wv_out, ipw_out, ipb_out, ow_out, ob_out,
        lin_w, lin_b, McatbT, bcat, PcatbT, bh);

    gemm_mfma<128, false><<<dim3(256, 6), 256, 0, stream>>>(
        Xb, McatbT, bcat, QKVb, 768);

    attn_kernel<<<NNODE * 2 / 4, 256, 0, stream>>>(
        QKVb, in_idx, out_idx, in_mask, out_mask, CTXb);

    gemm_mfma<256, true><<<dim3(256, 1), 256, 0, stream>>>(
        CTXb, PcatbT, bh, (float*)d_out, 128);
}